// Round 11
// baseline (242.484 us; speedup 1.0000x reference)
//
#include <hip/hip_runtime.h>
#include <math.h>

#define B_    256
#define S_    128
#define ENCD  1024
#define DECU  512
#define UNITS 1024
#define VOCAB 32000
#define EMB_  300
#define INDIM 1324   // ENCD + EMB
#define KPADX 1344   // INDIM padded to 64
#define G3    3072   // 3*UNITS

typedef __bf16 bf16x8 __attribute__((ext_vector_type(8)));
typedef __bf16 bf16x4 __attribute__((ext_vector_type(4)));
typedef __bf16 bf16x2 __attribute__((ext_vector_type(2)));
typedef float  f32x4  __attribute__((ext_vector_type(4)));

#define MFMA16(a, b, c) __builtin_amdgcn_mfma_f32_16x16x32_bf16((a), (b), (c), 0, 0, 0)

// LDS tile row stride 64 bf16 (128B), XOR-swizzled 16B slots: conflict-free b128 (measured 0 since R5).
__device__ __forceinline__ int swz(int row, int e) { return row * 64 + (e ^ ((row & 7) << 3)); }

// async global->LDS 16B/lane; LDS dest wave-uniform base + lane*16 (linear).
__device__ __forceinline__ void gl_lds16(const void* g, void* l) {
  __builtin_amdgcn_global_load_lds((const __attribute__((address_space(1))) void*)g,
                                   (__attribute__((address_space(3))) void*)l, 16, 0, 0);
}

__device__ __forceinline__ float fast_tanh(float x) {
  x = fminf(fmaxf(x, -15.f), 15.f);
  float e = __expf(2.f * x);
  return (e - 1.f) / (e + 1.f);
}

// ---------------- merged prep: enc f32->bf16 (blocks 0..4095, 4 iters) + state (4096..4351) ----------------
__global__ __launch_bounds__(256) void k_prep(const float* __restrict__ enc,
                                              __bf16* __restrict__ enc_bf,
                                              const float* __restrict__ state,
                                              __bf16* __restrict__ state_bf) {
  int bid = blockIdx.x;
  if (bid < 4096) {
    for (int g = bid * 256 + threadIdx.x; g < (B_ * S_ * ENCD) / 8; g += 4096 * 256) {
      const float* p = enc + (size_t)g * 8;
      float4 f0 = *(const float4*)p;
      float4 f1 = *(const float4*)(p + 4);
      bf16x8 o = {(__bf16)f0.x, (__bf16)f0.y, (__bf16)f0.z, (__bf16)f0.w,
                  (__bf16)f1.x, (__bf16)f1.y, (__bf16)f1.z, (__bf16)f1.w};
      *(bf16x8*)(enc_bf + (size_t)g * 8) = o;
    }
  } else {
    int i4 = (bid - 4096) * 256 + threadIdx.x;   // 65536 float4
    float4 f = *(const float4*)(state + (size_t)i4 * 4);
    bf16x4 o = {(__bf16)f.x, (__bf16)f.y, (__bf16)f.z, (__bf16)f.w};
    *(bf16x4*)(state_bf + (size_t)i4 * 4) = o;
  }
}

// ---------------- transpose+convert W1 [1024][512] f32 -> W1t [512][1024] bf16 ----------------
__global__ __launch_bounds__(1024) void k_w1t(const float* __restrict__ W1,
                                              __bf16* __restrict__ W1t) {
  int n = blockIdx.x;      // 512
  int k = threadIdx.x;     // 1024
  W1t[(size_t)n * 1024 + k] = (__bf16)W1[(size_t)k * 512 + n];
}

// ============ GEMM v2: dbuf + issue-early + SINGLE barrier per K-iter ============
// C[M][N] = A_bf[M][ldaK] @ B_f32[K][N] + bias. BN=64, BK=64, 512 thr (8 waves).
// Race-free: within an iter, MFMA reads buf[cur] while reg-staged writes go to buf[cur^1].
template <int BM>
__global__ __launch_bounds__(512) void k_gemm2(const __bf16* __restrict__ A, int ldaK,
                                               const float* __restrict__ B,
                                               const float* __restrict__ bias,
                                               float* __restrict__ C, int K, int N) {
  constexpr int WR = (BM == 64) ? 2 : 4;
  constexpr int WN = 8 / WR;
  constexpr int MI = BM / (WR * 16);
  constexpr int NI = 64 / (WN * 16);
  __shared__ __align__(16) __bf16 As[2][BM * 64];
  __shared__ __align__(16) __bf16 Bs[2][64 * 64];
  int tid = threadIdx.x, lane = tid & 63, w = tid >> 6;
  int wr = w / WN, wn = w % WN;
  int m0 = blockIdx.x * BM, n0 = blockIdx.y * 64;
  int lrow = lane & 15, lk = (lane >> 4) * 8;
  int r0 = wr * MI * 16, c0 = wn * NI * 16;
  f32x4 acc[MI][NI] = {};

  constexpr int ACH = BM / 64;        // bf16x8 chunks per thread (A)
  constexpr int TPR = 8 / ACH;        // threads per A row
  bf16x8 pfa[ACH];
  float pfb[8];
  int am = tid / TPR, aks = (tid % TPR) * (ACH * 8);
  const __bf16* arow = A + (size_t)(m0 + am) * ldaK + aks;
  int bn = tid & 63, bks = (tid >> 6) * 8;
  int nk = (K + 63) >> 6;

  // prologue: tile 0 -> buf 0
#pragma unroll
  for (int c = 0; c < ACH; ++c) pfa[c] = *(const bf16x8*)(arow + c * 8);
#pragma unroll
  for (int i = 0; i < 8; ++i) { int k = bks + i; pfb[i] = (k < K) ? B[(size_t)k * N + n0 + bn] : 0.f; }
#pragma unroll
  for (int c = 0; c < ACH; ++c) *(bf16x8*)&As[0][swz(am, aks + c * 8)] = pfa[c];
  {
    __bf16 tb[8];
#pragma unroll
    for (int i = 0; i < 8; ++i) tb[i] = (__bf16)pfb[i];
    *(bf16x8*)&Bs[0][swz(bn, bks)] = *(bf16x8*)&tb[0];
  }
  __syncthreads();

  int cur = 0;
  for (int it = 0; it < nk; ++it) {
    bool more = (it + 1 < nk);
    if (more) {                         // issue next-tile loads BEFORE MFMA
      int k0 = (it + 1) * 64;
#pragma unroll
      for (int c = 0; c < ACH; ++c) pfa[c] = *(const bf16x8*)(arow + k0 + c * 8);
#pragma unroll
      for (int i = 0; i < 8; ++i) { int k = k0 + bks + i; pfb[i] = (k < K) ? B[(size_t)k * N + n0 + bn] : 0.f; }
    }
    const __bf16* Ac = As[cur];
    const __bf16* Bc = Bs[cur];
#pragma unroll
    for (int kk = 0; kk < 64; kk += 32) {
      bf16x8 av[MI], bv[NI];
#pragma unroll
      for (int mi = 0; mi < MI; ++mi) { int r = r0 + mi * 16 + lrow; av[mi] = *(const bf16x8*)&Ac[swz(r, kk + lk)]; }
#pragma unroll
      for (int ni = 0; ni < NI; ++ni) { int r = c0 + ni * 16 + lrow; bv[ni] = *(const bf16x8*)&Bc[swz(r, kk + lk)]; }
#pragma unroll
      for (int mi = 0; mi < MI; ++mi)
#pragma unroll
        for (int ni = 0; ni < NI; ++ni) acc[mi][ni] = MFMA16(av[mi], bv[ni], acc[mi][ni]);
    }
    if (more) {                         // write next tile into the OTHER buffer
#pragma unroll
      for (int c = 0; c < ACH; ++c) *(bf16x8*)&As[cur ^ 1][swz(am, aks + c * 8)] = pfa[c];
      __bf16 tb[8];
#pragma unroll
      for (int i = 0; i < 8; ++i) tb[i] = (__bf16)pfb[i];
      *(bf16x8*)&Bs[cur ^ 1][swz(bn, bks)] = *(bf16x8*)&tb[0];
      __syncthreads();                  // the ONLY barrier per iter
      cur ^= 1;
    }
  }
#pragma unroll
  for (int mi = 0; mi < MI; ++mi)
#pragma unroll
    for (int ni = 0; ni < NI; ++ni) {
      int colg = n0 + c0 + ni * 16 + lrow;
      float bvv = bias[colg];
#pragma unroll
      for (int reg = 0; reg < 4; ++reg) {
        int rowg = m0 + r0 + mi * 16 + (lane >> 4) * 4 + reg;
        C[(size_t)rowg * N + colg] = acc[mi][ni][reg] + bvv;
      }
    }
}

// ============ score v7: dbuf gl_lds + issue-early + single barrier ============
// A = enc_bf, B = W1t, 128x128 tile, BK=64, 4 waves, 65KB LDS (2 blocks/CU).
// grid (256 b, 4 j-tiles). Output: sc_part[row][4] (pre-softmax, V-contracted).
__global__ __launch_bounds__(256) void k_score7(const __bf16* __restrict__ enc_bf,
                                                const __bf16* __restrict__ W1t,
                                                const float* __restrict__ b1,
                                                const float* __restrict__ q,
                                                const float* __restrict__ V,
                                                float* __restrict__ sc_part) {
  __shared__ __align__(16) __bf16 As[2][128 * 64];
  __shared__ __align__(16) __bf16 Bs[2][128 * 64];
  __shared__ float red[2][128];
  int b = blockIdx.x, by = blockIdx.y;
  int m0 = b * 128, n0 = by * 128;
  int tid = threadIdx.x, lane = tid & 63, w = tid >> 6;
  int wr = w >> 1, wn = w & 1;
  int lrow = lane & 15, lk = (lane >> 4) * 8;
  int r0 = wr * 64, c0 = wn * 64;
  f32x4 acc[4][4] = {};

  // gl_lds geometry: wave w stages 16B-chunks [w*4, w*4+4) of each 8KB tile.
  // chunk ch, lane l -> LDS row ch*8 + (l>>3), physical slot l&7.
  // Swizzled content: physical slot p of row r holds logical slot p ^ (r&7).
  int srow = lane >> 3;
  int sslot = (lane & 7) ^ (srow & 7);
  const __bf16* asrc[4];
  const __bf16* bsrc[4];
#pragma unroll
  for (int c = 0; c < 4; ++c) {
    int row = (w * 4 + c) * 8 + srow;
    asrc[c] = enc_bf + (size_t)(m0 + row) * 1024 + sslot * 8;
    bsrc[c] = W1t + (size_t)(n0 + row) * 1024 + sslot * 8;
  }

  // prologue: tile 0 -> buf 0
#pragma unroll
  for (int c = 0; c < 4; ++c) gl_lds16(asrc[c], &As[0][(w * 4 + c) * 512]);
#pragma unroll
  for (int c = 0; c < 4; ++c) gl_lds16(bsrc[c], &Bs[0][(w * 4 + c) * 512]);
  __syncthreads();

  int cur = 0;
  for (int it = 0; it < 16; ++it) {
    bool more = (it + 1 < 16);
    if (more) {                         // issue next-tile gl_lds into OTHER buffer, pre-MFMA
      int k0 = (it + 1) * 64;
#pragma unroll
      for (int c = 0; c < 4; ++c) gl_lds16(asrc[c] + k0, &As[cur ^ 1][(w * 4 + c) * 512]);
#pragma unroll
      for (int c = 0; c < 4; ++c) gl_lds16(bsrc[c] + k0, &Bs[cur ^ 1][(w * 4 + c) * 512]);
    }
    const __bf16* Ac = As[cur];
    const __bf16* Bc = Bs[cur];
#pragma unroll
    for (int kk = 0; kk < 64; kk += 32) {
      bf16x8 av[4], bv[4];
#pragma unroll
      for (int mi = 0; mi < 4; ++mi) { int r = r0 + mi * 16 + lrow; av[mi] = *(const bf16x8*)&Ac[swz(r, kk + lk)]; }
#pragma unroll
      for (int ni = 0; ni < 4; ++ni) { int r = c0 + ni * 16 + lrow; bv[ni] = *(const bf16x8*)&Bc[swz(r, kk + lk)]; }
#pragma unroll
      for (int mi = 0; mi < 4; ++mi)
#pragma unroll
        for (int ni = 0; ni < 4; ++ni) acc[mi][ni] = MFMA16(av[mi], bv[ni], acc[mi][ni]);
    }
    if (more) {
      __syncthreads();                  // the ONLY barrier: drains gl_lds (vmcnt) + publishes
      cur ^= 1;
    }
  }
  // ---- epilogue: tanh + dot V over this block's 128 j
  float psum[4][4] = {};
#pragma unroll
  for (int mi = 0; mi < 4; ++mi)
#pragma unroll
    for (int ni = 0; ni < 4; ++ni) {
      int j = n0 + c0 + ni * 16 + lrow;
      float vj = V[j], b1j = b1[j], qv = q[(size_t)b * DECU + j];
#pragma unroll
      for (int reg = 0; reg < 4; ++reg)
        psum[mi][reg] += vj * fast_tanh(acc[mi][ni][reg] + b1j + qv);
    }
#pragma unroll
  for (int off = 1; off < 16; off <<= 1)
#pragma unroll
    for (int mi = 0; mi < 4; ++mi)
#pragma unroll
      for (int reg = 0; reg < 4; ++reg)
        psum[mi][reg] += __shfl_xor(psum[mi][reg], off);
  __syncthreads();   // acc reads from LDS done; red reuse safe
  if (lrow == 0) {
#pragma unroll
    for (int mi = 0; mi < 4; ++mi)
#pragma unroll
      for (int reg = 0; reg < 4; ++reg)
        red[wn][r0 + mi * 16 + (lane >> 4) * 4 + reg] = psum[mi][reg];
  }
  __syncthreads();
  if (tid < 128)
    sc_part[((size_t)b * 128 + tid) * 4 + by] = red[0][tid] + red[1][tid];
}

// ---------------- ctx v4: softmax + context (bf16 enc) + xi; grid (256 b, 8 col-chunks) ----------------
__global__ __launch_bounds__(256) void k_ctx4(const float* __restrict__ sc_part,
                                              const float* __restrict__ bV,
                                              const __bf16* __restrict__ enc_bf,
                                              const int* __restrict__ x,
                                              const float* __restrict__ emb,
                                              float* __restrict__ attn_out,
                                              __bf16* __restrict__ xi_bf) {
  int b = blockIdx.x, chunk = blockIdx.y, t = threadIdx.x;
  int lane = t & 63, w = t >> 6;
  __shared__ float a_s[S_];
  __shared__ float part[4][128];
  if (t < S_) {
    float4 p = *(const float4*)&sc_part[((size_t)b * 128 + t) * 4];
    a_s[t] = bV[0] + p.x + p.y + p.z + p.w;
  }
  __syncthreads();
  float mx = -INFINITY;
  for (int s = 0; s < S_; ++s) mx = fmaxf(mx, a_s[s]);
  float sum = 0.f;
  for (int s = 0; s < S_; ++s) sum += __expf(a_s[s] - mx);
  float inv = 1.f / sum;
  __syncthreads();
  if (t < S_) {
    float av = __expf(a_s[t] - mx) * inv;
    a_s[t] = av;
    if (chunk == 0) attn_out[(size_t)b * S_ + t] = av;
  }
  __syncthreads();
  int c0 = chunk * 128;
  float a0 = 0.f, a1 = 0.f;
  const __bf16* eb = enc_bf + ((size_t)b * S_ + w * 32) * ENCD + c0 + lane * 2;
#pragma unroll 8
  for (int s = 0; s < 32; ++s) {
    bf16x2 e = *(const bf16x2*)(eb + (size_t)s * ENCD);
    float av = a_s[w * 32 + s];
    a0 = fmaf(av, (float)e[0], a0);
    a1 = fmaf(av, (float)e[1], a1);
  }
  part[w][lane * 2 + 0] = a0;
  part[w][lane * 2 + 1] = a1;
  __syncthreads();
  if (t < 128) {
    float v = part[0][t] + part[1][t] + part[2][t] + part[3][t];
    xi_bf[(size_t)b * KPADX + c0 + t] = (__bf16)v;
  }
  if (chunk == 0) {
    int xb = x[b];
    if (t < 75) {
      float4 f = *(const float4*)&emb[(size_t)xb * EMB_ + t * 4];
      bf16x4 o4 = {(__bf16)f.x, (__bf16)f.y, (__bf16)f.z, (__bf16)f.w};
      *(bf16x4*)&xi_bf[(size_t)b * KPADX + ENCD + t * 4] = o4;
    } else if (t < 80) {
      bf16x4 z = {(__bf16)0.f, (__bf16)0.f, (__bf16)0.f, (__bf16)0.f};
      *(bf16x4*)&xi_bf[(size_t)b * KPADX + INDIM + (t - 75) * 4] = z;
    }
  }
}

// ---------------- GRU gates (+ h in bf16) ----------------
__global__ __launch_bounds__(256) void k_gates(const float* __restrict__ mx,
                                               const float* __restrict__ mh,
                                               const float* __restrict__ state,
                                               float* __restrict__ h_out,
                                               __bf16* __restrict__ h_bf) {
  int idx = blockIdx.x * 256 + threadIdx.x;
  int b = idx >> 10, j = idx & 1023;
  const float* mxr = mx + (size_t)b * G3;
  const float* mhr = mh + (size_t)b * G3;
  float z = 1.f / (1.f + __expf(-(mxr[j] + mhr[j])));
  float r = 1.f / (1.f + __expf(-(mxr[UNITS + j] + mhr[UNITS + j])));
  float hh = tanhf(mxr[2 * UNITS + j] + r * mhr[2 * UNITS + j]);
  float st = state[idx];
  float h = z * st + (1.f - z) * hh;
  h_out[idx] = h;
  h_bf[idx] = (__bf16)h;
}

// ---------------- register-resident vocab softmax ----------------
__global__ __launch_bounds__(1024) void k_softmax(float* __restrict__ logits) {
  int b = blockIdx.x, t = threadIdx.x;
  int lane = t & 63, w = t >> 6;
  float4* row4 = (float4*)(logits + (size_t)b * VOCAB);  // 8000 float4
  __shared__ float redm[16];
  __shared__ float reds[16];
  float4 v[8];
  float m = -INFINITY;
#pragma unroll
  for (int i = 0; i < 8; ++i) {
    int i4 = i * 1024 + t;
    if (i4 < 8000) {
      v[i] = row4[i4];
      m = fmaxf(m, fmaxf(fmaxf(v[i].x, v[i].y), fmaxf(v[i].z, v[i].w)));
    } else {
      v[i] = make_float4(-INFINITY, -INFINITY, -INFINITY, -INFINITY);
    }
  }
#pragma unroll
  for (int o = 32; o >= 1; o >>= 1) m = fmaxf(m, __shfl_xor(m, o));
  if (lane == 0) redm[w] = m;
  __syncthreads();
  float m2 = -INFINITY;
#pragma unroll
  for (int i = 0; i < 16; ++i) m2 = fmaxf(m2, redm[i]);
  float s = 0.f;
#pragma unroll
  for (int i = 0; i < 8; ++i) {
    v[i].x = __expf(v[i].x - m2);
    v[i].y = __expf(v[i].y - m2);
    v[i].z = __expf(v[i].z - m2);
    v[i].w = __expf(v[i].w - m2);
    s += v[i].x + v[i].y + v[i].z + v[i].w;
  }
#pragma unroll
  for (int o = 32; o >= 1; o >>= 1) s += __shfl_xor(s, o);
  if (lane == 0) reds[w] = s;
  __syncthreads();
  float s2 = 0.f;
#pragma unroll
  for (int i = 0; i < 16; ++i) s2 += reds[i];
  float inv = 1.f / s2;
#pragma unroll
  for (int i = 0; i < 8; ++i) {
    int i4 = i * 1024 + t;
    if (i4 < 8000)
      row4[i4] = make_float4(v[i].x * inv, v[i].y * inv, v[i].z * inv, v[i].w * inv);
  }
}

extern "C" void kernel_launch(void* const* d_in, const int* in_sizes, int n_in,
                              void* d_out, int out_size, void* d_ws, size_t ws_size,
                              hipStream_t stream) {
  const int*   x     = (const int*)d_in[0];
  const float* state = (const float*)d_in[1];
  const float* enc   = (const float*)d_in[2];
  const float* emb   = (const float*)d_in[3];
  const float* W1    = (const float*)d_in[4];
  const float* b1    = (const float*)d_in[5];
  const float* W2    = (const float*)d_in[6];
  const float* b2    = (const float*)d_in[7];
  const float* V     = (const float*)d_in[8];
  const float* bV    = (const float*)d_in[9];
  const float* gru_k = (const float*)d_in[10];
  const float* gru_rk= (const float*)d_in[11];
  const float* gru_b = (const float*)d_in[12];
  const float* fc_W  = (const float*)d_in[13];
  const float* fc_b  = (const float*)d_in[14];

  float* out   = (float*)d_out;
  float* probs = out;                               // 256*32000
  float* h_out = out + (size_t)B_ * VOCAB;          // 256*1024
  float* attn  = h_out + (size_t)B_ * UNITS;        // 256*128

  // ws layout (bytes), 16B-aligned offsets:
  char* wsb = (char*)d_ws;
  const size_t ENC_BF_BYTES = (size_t)B_ * S_ * ENCD * 2;        // 67,108,864
  __bf16* enc_bf  = (__bf16*)wsb;
  __bf16* W1t     = (__bf16*)(wsb + ENC_BF_BYTES);                // 1MB
  __bf16* state_bf= (__bf16*)(wsb + ENC_BF_BYTES + 1048576);      // 0.5MB
  __bf16* xi_bf   = (__bf16*)(wsb + ENC_BF_BYTES + 1572864);      // 688128
  __bf16* h_bf    = (__bf16*)(wsb + ENC_BF_BYTES + 2260992);      // 0.5MB
  float*  q       = (float*)(wsb + ENC_BF_BYTES + 2785280);       // 0.5MB
  float*  sc_part = (float*)(wsb + ENC_BF_BYTES + 3309568);       // 0.5MB
  float*  mx      = (float*)(wsb + ENC_BF_BYTES + 3833856);       // 3MB
  float*  mh      = (float*)(wsb + ENC_BF_BYTES + 6979584);       // 3MB

  k_prep<<<4352, 256, 0, stream>>>(enc, enc_bf, state, state_bf);
  k_w1t<<<512, 1024, 0, stream>>>(W1, W1t);
  // q = state @ W2 + b2
  k_gemm2<64><<<dim3(4, 8), 512, 0, stream>>>(state_bf, UNITS, W2, b2, q, UNITS, DECU);
  // score partials (dbuf gl_lds, single barrier)
  k_score7<<<dim3(B_, 4), 256, 0, stream>>>(enc_bf, W1t, b1, q, V, sc_part);
  // softmax + context + xi
  k_ctx4<<<dim3(B_, 8), 256, 0, stream>>>(sc_part, bV, enc_bf, x, emb, attn, xi_bf);
  // GRU GEMMs
  k_gemm2<64><<<dim3(4, 48), 512, 0, stream>>>(xi_bf, KPADX, gru_k, gru_b, mx, INDIM, G3);
  k_gemm2<64><<<dim3(4, 48), 512, 0, stream>>>(state_bf, UNITS, gru_rk, gru_b + G3, mh, UNITS, G3);
  // gates -> h
  k_gates<<<(B_ * UNITS) / 256, 256, 0, stream>>>(mx, mh, state, h_out, h_bf);
  // FC logits
  k_gemm2<256><<<dim3(1, VOCAB / 64), 512, 0, stream>>>(h_bf, UNITS, fc_W, fc_b, probs, UNITS, VOCAB);
  // vocab softmax
  k_softmax<<<B_, 1024, 0, stream>>>(probs);
}

// Round 12
// 231.748 us; speedup vs baseline: 1.0463x; 1.0463x over previous
//
#include <hip/hip_runtime.h>
#include <math.h>

#define B_    256
#define S_    128
#define ENCD  1024
#define DECU  512
#define UNITS 1024
#define VOCAB 32000
#define EMB_  300
#define INDIM 1324   // ENCD + EMB
#define KPADX 1344   // INDIM padded to 64
#define G3    3072   // 3*UNITS

typedef __bf16 bf16x8 __attribute__((ext_vector_type(8)));
typedef __bf16 bf16x4 __attribute__((ext_vector_type(4)));
typedef __bf16 bf16x2 __attribute__((ext_vector_type(2)));
typedef float  f32x4  __attribute__((ext_vector_type(4)));

#define MFMA16(a, b, c) __builtin_amdgcn_mfma_f32_16x16x32_bf16((a), (b), (c), 0, 0, 0)

// LDS tile row stride 64 bf16 (128B), XOR-swizzled 16B slots: conflict-free b128 (measured 0 since R5).
__device__ __forceinline__ int swz(int row, int e) { return row * 64 + (e ^ ((row & 7) << 3)); }

// async global->LDS 16B/lane; LDS dest wave-uniform base + lane*16 (linear).
__device__ __forceinline__ void gl_lds16(const void* g, void* l) {
  __builtin_amdgcn_global_load_lds((const __attribute__((address_space(1))) void*)g,
                                   (__attribute__((address_space(3))) void*)l, 16, 0, 0);
}

__device__ __forceinline__ float fast_tanh(float x) {
  x = fminf(fmaxf(x, -15.f), 15.f);
  float e = __expf(2.f * x);
  return (e - 1.f) / (e + 1.f);
}

// ---------------- merged prep: enc f32->bf16 + state f32->bf16 ----------------
__global__ __launch_bounds__(256) void k_prep(const float* __restrict__ enc,
                                              __bf16* __restrict__ enc_bf,
                                              const float* __restrict__ state,
                                              __bf16* __restrict__ state_bf) {
  int bid = blockIdx.x;
  if (bid < 4096) {
    for (int g = bid * 256 + threadIdx.x; g < (B_ * S_ * ENCD) / 8; g += 4096 * 256) {
      const float* p = enc + (size_t)g * 8;
      float4 f0 = *(const float4*)p;
      float4 f1 = *(const float4*)(p + 4);
      bf16x8 o = {(__bf16)f0.x, (__bf16)f0.y, (__bf16)f0.z, (__bf16)f0.w,
                  (__bf16)f1.x, (__bf16)f1.y, (__bf16)f1.z, (__bf16)f1.w};
      *(bf16x8*)(enc_bf + (size_t)g * 8) = o;
    }
  } else {
    int i4 = (bid - 4096) * 256 + threadIdx.x;   // 65536 float4
    float4 f = *(const float4*)(state + (size_t)i4 * 4);
    bf16x4 o = {(__bf16)f.x, (__bf16)f.y, (__bf16)f.z, (__bf16)f.w};
    *(bf16x4*)(state_bf + (size_t)i4 * 4) = o;
  }
}

// ---------------- transpose+convert W1 [1024][512] f32 -> W1t [512][1024] bf16 ----------------
__global__ __launch_bounds__(1024) void k_w1t(const float* __restrict__ W1,
                                              __bf16* __restrict__ W1t) {
  int n = blockIdx.x;      // 512
  int k = threadIdx.x;     // 1024
  W1t[(size_t)n * 1024 + k] = (__bf16)W1[(size_t)k * 512 + n];
}

// ============ GEMM v2: dbuf + issue-early + single barrier (proven R11) ============
template <int BM>
__global__ __launch_bounds__(512) void k_gemm2(const __bf16* __restrict__ A, int ldaK,
                                               const float* __restrict__ B,
                                               const float* __restrict__ bias,
                                               float* __restrict__ C, int K, int N) {
  constexpr int WR = (BM == 64) ? 2 : 4;
  constexpr int WN = 8 / WR;
  constexpr int MI = BM / (WR * 16);
  constexpr int NI = 64 / (WN * 16);
  __shared__ __align__(16) __bf16 As[2][BM * 64];
  __shared__ __align__(16) __bf16 Bs[2][64 * 64];
  int tid = threadIdx.x, lane = tid & 63, w = tid >> 6;
  int wr = w / WN, wn = w % WN;
  int m0 = blockIdx.x * BM, n0 = blockIdx.y * 64;
  int lrow = lane & 15, lk = (lane >> 4) * 8;
  int r0 = wr * MI * 16, c0 = wn * NI * 16;
  f32x4 acc[MI][NI] = {};

  constexpr int ACH = BM / 64;
  constexpr int TPR = 8 / ACH;
  bf16x8 pfa[ACH];
  float pfb[8];
  int am = tid / TPR, aks = (tid % TPR) * (ACH * 8);
  const __bf16* arow = A + (size_t)(m0 + am) * ldaK + aks;
  int bn = tid & 63, bks = (tid >> 6) * 8;
  int nk = (K + 63) >> 6;

#pragma unroll
  for (int c = 0; c < ACH; ++c) pfa[c] = *(const bf16x8*)(arow + c * 8);
#pragma unroll
  for (int i = 0; i < 8; ++i) { int k = bks + i; pfb[i] = (k < K) ? B[(size_t)k * N + n0 + bn] : 0.f; }
#pragma unroll
  for (int c = 0; c < ACH; ++c) *(bf16x8*)&As[0][swz(am, aks + c * 8)] = pfa[c];
  {
    __bf16 tb[8];
#pragma unroll
    for (int i = 0; i < 8; ++i) tb[i] = (__bf16)pfb[i];
    *(bf16x8*)&Bs[0][swz(bn, bks)] = *(bf16x8*)&tb[0];
  }
  __syncthreads();

  int cur = 0;
  for (int it = 0; it < nk; ++it) {
    bool more = (it + 1 < nk);
    if (more) {
      int k0 = (it + 1) * 64;
#pragma unroll
      for (int c = 0; c < ACH; ++c) pfa[c] = *(const bf16x8*)(arow + k0 + c * 8);
#pragma unroll
      for (int i = 0; i < 8; ++i) { int k = k0 + bks + i; pfb[i] = (k < K) ? B[(size_t)k * N + n0 + bn] : 0.f; }
    }
    const __bf16* Ac = As[cur];
    const __bf16* Bc = Bs[cur];
#pragma unroll
    for (int kk = 0; kk < 64; kk += 32) {
      bf16x8 av[MI], bv[NI];
#pragma unroll
      for (int mi = 0; mi < MI; ++mi) { int r = r0 + mi * 16 + lrow; av[mi] = *(const bf16x8*)&Ac[swz(r, kk + lk)]; }
#pragma unroll
      for (int ni = 0; ni < NI; ++ni) { int r = c0 + ni * 16 + lrow; bv[ni] = *(const bf16x8*)&Bc[swz(r, kk + lk)]; }
#pragma unroll
      for (int mi = 0; mi < MI; ++mi)
#pragma unroll
        for (int ni = 0; ni < NI; ++ni) acc[mi][ni] = MFMA16(av[mi], bv[ni], acc[mi][ni]);
    }
    if (more) {
#pragma unroll
      for (int c = 0; c < ACH; ++c) *(bf16x8*)&As[cur ^ 1][swz(am, aks + c * 8)] = pfa[c];
      __bf16 tb[8];
#pragma unroll
      for (int i = 0; i < 8; ++i) tb[i] = (__bf16)pfb[i];
      *(bf16x8*)&Bs[cur ^ 1][swz(bn, bks)] = *(bf16x8*)&tb[0];
      __syncthreads();
      cur ^= 1;
    }
  }
#pragma unroll
  for (int mi = 0; mi < MI; ++mi)
#pragma unroll
    for (int ni = 0; ni < NI; ++ni) {
      int colg = n0 + c0 + ni * 16 + lrow;
      float bvv = bias[colg];
#pragma unroll
      for (int reg = 0; reg < 4; ++reg) {
        int rowg = m0 + r0 + mi * 16 + (lane >> 4) * 4 + reg;
        C[(size_t)rowg * N + colg] = acc[mi][ni][reg] + bvv;
      }
    }
}

// ============ GEMM dual-output: same A, two B/bias/C sets (mh: N1 cols, q: N2 cols) ============
__global__ __launch_bounds__(512) void k_gemm2d(const __bf16* __restrict__ A, int ldaK,
                                                const float* __restrict__ B1,
                                                const float* __restrict__ bias1,
                                                float* __restrict__ C1, int N1,
                                                const float* __restrict__ B2,
                                                const float* __restrict__ bias2,
                                                float* __restrict__ C2, int N2,
                                                int K) {
  constexpr int BM = 64, MI = 2, NI = 1;
  __shared__ __align__(16) __bf16 As[2][BM * 64];
  __shared__ __align__(16) __bf16 Bs[2][64 * 64];
  int tid = threadIdx.x, lane = tid & 63, w = tid >> 6;
  int wr = w >> 2, wn = w & 3;
  int m0 = blockIdx.x * BM;
  int n0 = blockIdx.y * 64;
  const float* B; const float* bias; float* C; int N;
  if (n0 < N1) { B = B1; bias = bias1; C = C1; N = N1; }
  else         { B = B2; bias = bias2; C = C2; N = N2; n0 -= N1; }
  int lrow = lane & 15, lk = (lane >> 4) * 8;
  int r0 = wr * MI * 16, c0 = wn * NI * 16;
  f32x4 acc[MI][NI] = {};

  bf16x8 pfa;
  float pfb[8];
  int am = tid >> 3, aks = (tid & 7) * 8;
  const __bf16* arow = A + (size_t)(m0 + am) * ldaK + aks;
  int bn = tid & 63, bks = (tid >> 6) * 8;
  int nk = (K + 63) >> 6;

  pfa = *(const bf16x8*)(arow);
#pragma unroll
  for (int i = 0; i < 8; ++i) { int k = bks + i; pfb[i] = (k < K) ? B[(size_t)k * N + n0 + bn] : 0.f; }
  *(bf16x8*)&As[0][swz(am, aks)] = pfa;
  {
    __bf16 tb[8];
#pragma unroll
    for (int i = 0; i < 8; ++i) tb[i] = (__bf16)pfb[i];
    *(bf16x8*)&Bs[0][swz(bn, bks)] = *(bf16x8*)&tb[0];
  }
  __syncthreads();

  int cur = 0;
  for (int it = 0; it < nk; ++it) {
    bool more = (it + 1 < nk);
    if (more) {
      int k0 = (it + 1) * 64;
      pfa = *(const bf16x8*)(arow + k0);
#pragma unroll
      for (int i = 0; i < 8; ++i) { int k = k0 + bks + i; pfb[i] = (k < K) ? B[(size_t)k * N + n0 + bn] : 0.f; }
    }
    const __bf16* Ac = As[cur];
    const __bf16* Bc = Bs[cur];
#pragma unroll
    for (int kk = 0; kk < 64; kk += 32) {
      bf16x8 av[MI], bv[NI];
#pragma unroll
      for (int mi = 0; mi < MI; ++mi) { int r = r0 + mi * 16 + lrow; av[mi] = *(const bf16x8*)&Ac[swz(r, kk + lk)]; }
#pragma unroll
      for (int ni = 0; ni < NI; ++ni) { int r = c0 + ni * 16 + lrow; bv[ni] = *(const bf16x8*)&Bc[swz(r, kk + lk)]; }
#pragma unroll
      for (int mi = 0; mi < MI; ++mi)
#pragma unroll
        for (int ni = 0; ni < NI; ++ni) acc[mi][ni] = MFMA16(av[mi], bv[ni], acc[mi][ni]);
    }
    if (more) {
      *(bf16x8*)&As[cur ^ 1][swz(am, aks)] = pfa;
      __bf16 tb[8];
#pragma unroll
      for (int i = 0; i < 8; ++i) tb[i] = (__bf16)pfb[i];
      *(bf16x8*)&Bs[cur ^ 1][swz(bn, bks)] = *(bf16x8*)&tb[0];
      __syncthreads();
      cur ^= 1;
    }
  }
#pragma unroll
  for (int mi = 0; mi < MI; ++mi)
#pragma unroll
    for (int ni = 0; ni < NI; ++ni) {
      int colg = n0 + c0 + ni * 16 + lrow;
      float bvv = bias[colg];
#pragma unroll
      for (int reg = 0; reg < 4; ++reg) {
        int rowg = m0 + r0 + mi * 16 + (lane >> 4) * 4 + reg;
        C[(size_t)rowg * N + colg] = acc[mi][ni][reg] + bvv;
      }
    }
}

// ============ score v8: T4 counted-vmcnt 3-buffer pipeline ============
// 512 threads (8 waves), 128x128 tile, BK=64, 97KB LDS (1 block/CU).
// Loop: issue tile t+2 (gl_lds), MFMA tile t, s_waitcnt vmcnt(4) [t+1 ready,
// t+2 stays in flight], s_barrier. vmcnt never drains to 0 in steady state.
// Epilogue operands preloaded + vmcnt(0) BEFORE the loop so in-loop vmcnt
// counts only gl_lds (deterministic).
__global__ __launch_bounds__(512) void k_score8(const __bf16* __restrict__ enc_bf,
                                                const __bf16* __restrict__ W1t,
                                                const float* __restrict__ b1,
                                                const float* __restrict__ q,
                                                const float* __restrict__ V,
                                                float* __restrict__ sc_part) {
  __shared__ __align__(16) __bf16 As[3][128 * 64];
  __shared__ __align__(16) __bf16 Bs[3][128 * 64];
  __shared__ float red[2][128];
  int b = blockIdx.x, by = blockIdx.y;
  int m0 = b * 128, n0 = by * 128;
  int tid = threadIdx.x, lane = tid & 63, w = tid >> 6;
  int wr = w >> 1, wn = w & 1;
  int lrow = lane & 15, lk = (lane >> 4) * 8;
  int r0 = wr * 32, c0 = wn * 64;
  f32x4 acc[2][4] = {};

  // preload epilogue operands (drained before pipeline starts)
  float vj[4], b1j[4], qv[4];
#pragma unroll
  for (int ni = 0; ni < 4; ++ni) {
    int j = n0 + c0 + ni * 16 + lrow;
    vj[ni] = V[j]; b1j[ni] = b1[j]; qv[ni] = q[(size_t)b * DECU + j];
  }
  // staging geometry: wave w stages chunks {2w, 2w+1} (1KB each) of each 16KB tile.
  // chunk ch, lane l -> LDS row ch*8 + (l>>3), physical slot l&7; swizzled source
  // slot = (l&7) ^ ((l>>3)&7)  [validated R8-R10].
  int srow = lane >> 3;
  int sslot = (lane & 7) ^ (srow & 7);
  const __bf16* asrc[2];
  const __bf16* bsrc[2];
  int ch0 = w * 2;
#pragma unroll
  for (int c = 0; c < 2; ++c) {
    int row = (ch0 + c) * 8 + srow;
    asrc[c] = enc_bf + (size_t)(m0 + row) * 1024 + sslot * 8;
    bsrc[c] = W1t + (size_t)(n0 + row) * 1024 + sslot * 8;
  }
  asm volatile("s_waitcnt vmcnt(0)" ::: "memory");   // epilogue preloads drained

  // prologue: tiles 0,1 -> buf 0,1 (4 gl_lds per wave per tile)
#pragma unroll
  for (int t = 0; t < 2; ++t) {
    int k0 = t * 64;
#pragma unroll
    for (int c = 0; c < 2; ++c) {
      gl_lds16(asrc[c] + k0, &As[t][(ch0 + c) * 512]);
      gl_lds16(bsrc[c] + k0, &Bs[t][(ch0 + c) * 512]);
    }
  }
  asm volatile("s_waitcnt vmcnt(4)" ::: "memory");   // tile0 ready, tile1 in flight
  __builtin_amdgcn_s_barrier();

#pragma unroll
  for (int it = 0; it < 16; ++it) {
    if (it + 2 < 16) {                               // issue tile t+2
      int k0 = (it + 2) * 64, bi = (it + 2) % 3;
#pragma unroll
      for (int c = 0; c < 2; ++c) {
        gl_lds16(asrc[c] + k0, &As[bi][(ch0 + c) * 512]);
        gl_lds16(bsrc[c] + k0, &Bs[bi][(ch0 + c) * 512]);
      }
    }
    const __bf16* Ac = As[it % 3];
    const __bf16* Bc = Bs[it % 3];
#pragma unroll
    for (int kk = 0; kk < 64; kk += 32) {
      bf16x8 av[2], bv[4];
#pragma unroll
      for (int mi = 0; mi < 2; ++mi) { int r = r0 + mi * 16 + lrow; av[mi] = *(const bf16x8*)&Ac[swz(r, kk + lk)]; }
#pragma unroll
      for (int ni = 0; ni < 4; ++ni) { int r = c0 + ni * 16 + lrow; bv[ni] = *(const bf16x8*)&Bc[swz(r, kk + lk)]; }
#pragma unroll
      for (int mi = 0; mi < 2; ++mi)
#pragma unroll
        for (int ni = 0; ni < 4; ++ni) acc[mi][ni] = MFMA16(av[mi], bv[ni], acc[mi][ni]);
    }
    if (it < 15) {
      if (it < 14) asm volatile("s_waitcnt vmcnt(4)" ::: "memory");   // t+1 ready, t+2 flying
      else         asm volatile("s_waitcnt vmcnt(0)" ::: "memory");   // last prefetched tile
      __builtin_amdgcn_s_barrier();
    }
  }
  // ---- epilogue: tanh + dot V, 16-lane reduce, cross-wave combine
  float psum[2][4] = {};
#pragma unroll
  for (int mi = 0; mi < 2; ++mi)
#pragma unroll
    for (int ni = 0; ni < 4; ++ni) {
#pragma unroll
      for (int reg = 0; reg < 4; ++reg)
        psum[mi][reg] += vj[ni] * fast_tanh(acc[mi][ni][reg] + b1j[ni] + qv[ni]);
    }
#pragma unroll
  for (int off = 1; off < 16; off <<= 1)
#pragma unroll
    for (int mi = 0; mi < 2; ++mi)
#pragma unroll
      for (int reg = 0; reg < 4; ++reg)
        psum[mi][reg] += __shfl_xor(psum[mi][reg], off);
  __syncthreads();
  if (lrow == 0) {
#pragma unroll
    for (int mi = 0; mi < 2; ++mi)
#pragma unroll
      for (int reg = 0; reg < 4; ++reg)
        red[wn][r0 + mi * 16 + (lane >> 4) * 4 + reg] = psum[mi][reg];
  }
  __syncthreads();
  if (tid < 128)
    sc_part[((size_t)b * 128 + tid) * 4 + by] = red[0][tid] + red[1][tid];
}

// ---------------- ctx v4: softmax + context (bf16 enc) + xi; grid (256 b, 8 col-chunks) ----------------
__global__ __launch_bounds__(256) void k_ctx4(const float* __restrict__ sc_part,
                                              const float* __restrict__ bV,
                                              const __bf16* __restrict__ enc_bf,
                                              const int* __restrict__ x,
                                              const float* __restrict__ emb,
                                              float* __restrict__ attn_out,
                                              __bf16* __restrict__ xi_bf) {
  int b = blockIdx.x, chunk = blockIdx.y, t = threadIdx.x;
  int lane = t & 63, w = t >> 6;
  __shared__ float a_s[S_];
  __shared__ float part[4][128];
  if (t < S_) {
    float4 p = *(const float4*)&sc_part[((size_t)b * 128 + t) * 4];
    a_s[t] = bV[0] + p.x + p.y + p.z + p.w;
  }
  __syncthreads();
  float mx = -INFINITY;
  for (int s = 0; s < S_; ++s) mx = fmaxf(mx, a_s[s]);
  float sum = 0.f;
  for (int s = 0; s < S_; ++s) sum += __expf(a_s[s] - mx);
  float inv = 1.f / sum;
  __syncthreads();
  if (t < S_) {
    float av = __expf(a_s[t] - mx) * inv;
    a_s[t] = av;
    if (chunk == 0) attn_out[(size_t)b * S_ + t] = av;
  }
  __syncthreads();
  int c0 = chunk * 128;
  float a0 = 0.f, a1 = 0.f;
  const __bf16* eb = enc_bf + ((size_t)b * S_ + w * 32) * ENCD + c0 + lane * 2;
#pragma unroll 8
  for (int s = 0; s < 32; ++s) {
    bf16x2 e = *(const bf16x2*)(eb + (size_t)s * ENCD);
    float av = a_s[w * 32 + s];
    a0 = fmaf(av, (float)e[0], a0);
    a1 = fmaf(av, (float)e[1], a1);
  }
  part[w][lane * 2 + 0] = a0;
  part[w][lane * 2 + 1] = a1;
  __syncthreads();
  if (t < 128) {
    float v = part[0][t] + part[1][t] + part[2][t] + part[3][t];
    xi_bf[(size_t)b * KPADX + c0 + t] = (__bf16)v;
  }
  if (chunk == 0) {
    int xb = x[b];
    if (t < 75) {
      float4 f = *(const float4*)&emb[(size_t)xb * EMB_ + t * 4];
      bf16x4 o4 = {(__bf16)f.x, (__bf16)f.y, (__bf16)f.z, (__bf16)f.w};
      *(bf16x4*)&xi_bf[(size_t)b * KPADX + ENCD + t * 4] = o4;
    } else if (t < 80) {
      bf16x4 z = {(__bf16)0.f, (__bf16)0.f, (__bf16)0.f, (__bf16)0.f};
      *(bf16x4*)&xi_bf[(size_t)b * KPADX + INDIM + (t - 75) * 4] = z;
    }
  }
}

// ---------------- GRU gates (+ h in bf16) ----------------
__global__ __launch_bounds__(256) void k_gates(const float* __restrict__ mx,
                                               const float* __restrict__ mh,
                                               const float* __restrict__ state,
                                               float* __restrict__ h_out,
                                               __bf16* __restrict__ h_bf) {
  int idx = blockIdx.x * 256 + threadIdx.x;
  int b = idx >> 10, j = idx & 1023;
  const float* mxr = mx + (size_t)b * G3;
  const float* mhr = mh + (size_t)b * G3;
  float z = 1.f / (1.f + __expf(-(mxr[j] + mhr[j])));
  float r = 1.f / (1.f + __expf(-(mxr[UNITS + j] + mhr[UNITS + j])));
  float hh = tanhf(mxr[2 * UNITS + j] + r * mhr[2 * UNITS + j]);
  float st = state[idx];
  float h = z * st + (1.f - z) * hh;
  h_out[idx] = h;
  h_bf[idx] = (__bf16)h;
}

// ---------------- register-resident vocab softmax ----------------
__global__ __launch_bounds__(1024) void k_softmax(float* __restrict__ logits) {
  int b = blockIdx.x, t = threadIdx.x;
  int lane = t & 63, w = t >> 6;
  float4* row4 = (float4*)(logits + (size_t)b * VOCAB);  // 8000 float4
  __shared__ float redm[16];
  __shared__ float reds[16];
  float4 v[8];
  float m = -INFINITY;
#pragma unroll
  for (int i = 0; i < 8; ++i) {
    int i4 = i * 1024 + t;
    if (i4 < 8000) {
      v[i] = row4[i4];
      m = fmaxf(m, fmaxf(fmaxf(v[i].x, v[i].y), fmaxf(v[i].z, v[i].w)));
    } else {
      v[i] = make_float4(-INFINITY, -INFINITY, -INFINITY, -INFINITY);
    }
  }
#pragma unroll
  for (int o = 32; o >= 1; o >>= 1) m = fmaxf(m, __shfl_xor(m, o));
  if (lane == 0) redm[w] = m;
  __syncthreads();
  float m2 = -INFINITY;
#pragma unroll
  for (int i = 0; i < 16; ++i) m2 = fmaxf(m2, redm[i]);
  float s = 0.f;
#pragma unroll
  for (int i = 0; i < 8; ++i) {
    v[i].x = __expf(v[i].x - m2);
    v[i].y = __expf(v[i].y - m2);
    v[i].z = __expf(v[i].z - m2);
    v[i].w = __expf(v[i].w - m2);
    s += v[i].x + v[i].y + v[i].z + v[i].w;
  }
#pragma unroll
  for (int o = 32; o >= 1; o >>= 1) s += __shfl_xor(s, o);
  if (lane == 0) reds[w] = s;
  __syncthreads();
  float s2 = 0.f;
#pragma unroll
  for (int i = 0; i < 16; ++i) s2 += reds[i];
  float inv = 1.f / s2;
#pragma unroll
  for (int i = 0; i < 8; ++i) {
    int i4 = i * 1024 + t;
    if (i4 < 8000)
      row4[i4] = make_float4(v[i].x * inv, v[i].y * inv, v[i].z * inv, v[i].w * inv);
  }
}

extern "C" void kernel_launch(void* const* d_in, const int* in_sizes, int n_in,
                              void* d_out, int out_size, void* d_ws, size_t ws_size,
                              hipStream_t stream) {
  const int*   x     = (const int*)d_in[0];
  const float* state = (const float*)d_in[1];
  const float* enc   = (const float*)d_in[2];
  const float* emb   = (const float*)d_in[3];
  const float* W1    = (const float*)d_in[4];
  const float* b1    = (const float*)d_in[5];
  const float* W2    = (const float*)d_in[6];
  const float* b2    = (const float*)d_in[7];
  const float* V     = (const float*)d_in[8];
  const float* bV    = (const float*)d_in[9];
  const float* gru_k = (const float*)d_in[10];
  const float* gru_rk= (const float*)d_in[11];
  const float* gru_b = (const float*)d_in[12];
  const float* fc_W  = (const float*)d_in[13];
  const float* fc_b  = (const float*)d_in[14];

  float* out   = (float*)d_out;
  float* probs = out;                               // 256*32000
  float* h_out = out + (size_t)B_ * VOCAB;          // 256*1024
  float* attn  = h_out + (size_t)B_ * UNITS;        // 256*128

  // ws layout (bytes), 16B-aligned offsets:
  char* wsb = (char*)d_ws;
  const size_t ENC_BF_BYTES = (size_t)B_ * S_ * ENCD * 2;        // 67,108,864
  __bf16* enc_bf  = (__bf16*)wsb;
  __bf16* W1t     = (__bf16*)(wsb + ENC_BF_BYTES);                // 1MB
  __bf16* state_bf= (__bf16*)(wsb + ENC_BF_BYTES + 1048576);      // 0.5MB
  __bf16* xi_bf   = (__bf16*)(wsb + ENC_BF_BYTES + 1572864);      // 688128
  __bf16* h_bf    = (__bf16*)(wsb + ENC_BF_BYTES + 2260992);      // 0.5MB
  float*  q       = (float*)(wsb + ENC_BF_BYTES + 2785280);       // 0.5MB
  float*  sc_part = (float*)(wsb + ENC_BF_BYTES + 3309568);       // 0.5MB
  float*  mx      = (float*)(wsb + ENC_BF_BYTES + 3833856);       // 3MB
  float*  mh      = (float*)(wsb + ENC_BF_BYTES + 6979584);       // 3MB

  k_prep<<<4352, 256, 0, stream>>>(enc, enc_bf, state, state_bf);
  k_w1t<<<512, 1024, 0, stream>>>(W1, W1t);
  // mh = state @ gru_rk + gru_b[1]  AND  q = state @ W2 + b2  (fused dual GEMM)
  k_gemm2d<<<dim3(4, 56), 512, 0, stream>>>(state_bf, UNITS,
                                            gru_rk, gru_b + G3, mh, G3,
                                            W2, b2, q, DECU, UNITS);
  // score partials: counted-vmcnt 3-buffer pipeline
  k_score8<<<dim3(B_, 4), 512, 0, stream>>>(enc_bf, W1t, b1, q, V, sc_part);
  // softmax + context + xi
  k_ctx4<<<dim3(B_, 8), 256, 0, stream>>>(sc_part, bV, enc_bf, x, emb, attn, xi_bf);
  // GRU input GEMM
  k_gemm2<64><<<dim3(4, 48), 512, 0, stream>>>(xi_bf, KPADX, gru_k, gru_b, mx, INDIM, G3);
  // gates -> h
  k_gates<<<(B_ * UNITS) / 256, 256, 0, stream>>>(mx, mh, state, h_out, h_bf);
  // FC logits
  k_gemm2<256><<<dim3(1, VOCAB / 64), 512, 0, stream>>>(h_bf, UNITS, fc_W, fc_b, probs, UNITS, VOCAB);
  // vocab softmax
  k_softmax<<<B_, 1024, 0, stream>>>(probs);
}

// Round 13
// 224.213 us; speedup vs baseline: 1.0815x; 1.0336x over previous
//
#include <hip/hip_runtime.h>
#include <math.h>

#define B_    256
#define S_    128
#define ENCD  1024
#define DECU  512
#define UNITS 1024
#define VOCAB 32000
#define EMB_  300
#define INDIM 1324   // ENCD + EMB
#define KPADX 1344   // INDIM padded to 64
#define G3    3072   // 3*UNITS

typedef __bf16 bf16x8 __attribute__((ext_vector_type(8)));
typedef __bf16 bf16x4 __attribute__((ext_vector_type(4)));
typedef __bf16 bf16x2 __attribute__((ext_vector_type(2)));
typedef float  f32x4  __attribute__((ext_vector_type(4)));

#define MFMA16(a, b, c) __builtin_amdgcn_mfma_f32_16x16x32_bf16((a), (b), (c), 0, 0, 0)

// LDS tile row stride 64 bf16 (128B), XOR-swizzled 16B slots: conflict-free b128 (measured 0 since R5).
__device__ __forceinline__ int swz(int row, int e) { return row * 64 + (e ^ ((row & 7) << 3)); }

// async global->LDS 16B/lane; LDS dest wave-uniform base + lane*16 (linear).
__device__ __forceinline__ void gl_lds16(const void* g, void* l) {
  __builtin_amdgcn_global_load_lds((const __attribute__((address_space(1))) void*)g,
                                   (__attribute__((address_space(3))) void*)l, 16, 0, 0);
}

__device__ __forceinline__ float fast_tanh(float x) {
  x = fminf(fmaxf(x, -15.f), 15.f);
  float e = __expf(2.f * x);
  return (e - 1.f) / (e + 1.f);
}

// ---------------- merged prep: enc f32->bf16 + state f32->bf16 ----------------
__global__ __launch_bounds__(256) void k_prep(const float* __restrict__ enc,
                                              __bf16* __restrict__ enc_bf,
                                              const float* __restrict__ state,
                                              __bf16* __restrict__ state_bf) {
  int bid = blockIdx.x;
  if (bid < 4096) {
    for (int g = bid * 256 + threadIdx.x; g < (B_ * S_ * ENCD) / 8; g += 4096 * 256) {
      const float* p = enc + (size_t)g * 8;
      float4 f0 = *(const float4*)p;
      float4 f1 = *(const float4*)(p + 4);
      bf16x8 o = {(__bf16)f0.x, (__bf16)f0.y, (__bf16)f0.z, (__bf16)f0.w,
                  (__bf16)f1.x, (__bf16)f1.y, (__bf16)f1.z, (__bf16)f1.w};
      *(bf16x8*)(enc_bf + (size_t)g * 8) = o;
    }
  } else {
    int i4 = (bid - 4096) * 256 + threadIdx.x;   // 65536 float4
    float4 f = *(const float4*)(state + (size_t)i4 * 4);
    bf16x4 o = {(__bf16)f.x, (__bf16)f.y, (__bf16)f.z, (__bf16)f.w};
    *(bf16x4*)(state_bf + (size_t)i4 * 4) = o;
  }
}

// ---------------- transpose+convert W1 [1024][512] f32 -> W1t [512][1024] bf16 ----------------
__global__ __launch_bounds__(1024) void k_w1t(const float* __restrict__ W1,
                                              __bf16* __restrict__ W1t) {
  int n = blockIdx.x;      // 512
  int k = threadIdx.x;     // 1024
  W1t[(size_t)n * 1024 + k] = (__bf16)W1[(size_t)k * 512 + n];
}

// ============ GEMM v2: dbuf + issue-early + single barrier ============
template <int BM>
__global__ __launch_bounds__(512) void k_gemm2(const __bf16* __restrict__ A, int ldaK,
                                               const float* __restrict__ B,
                                               const float* __restrict__ bias,
                                               float* __restrict__ C, int K, int N) {
  constexpr int WR = (BM == 64) ? 2 : 4;
  constexpr int WN = 8 / WR;
  constexpr int MI = BM / (WR * 16);
  constexpr int NI = 64 / (WN * 16);
  __shared__ __align__(16) __bf16 As[2][BM * 64];
  __shared__ __align__(16) __bf16 Bs[2][64 * 64];
  int tid = threadIdx.x, lane = tid & 63, w = tid >> 6;
  int wr = w / WN, wn = w % WN;
  int m0 = blockIdx.x * BM, n0 = blockIdx.y * 64;
  int lrow = lane & 15, lk = (lane >> 4) * 8;
  int r0 = wr * MI * 16, c0 = wn * NI * 16;
  f32x4 acc[MI][NI] = {};

  constexpr int ACH = BM / 64;
  constexpr int TPR = 8 / ACH;
  bf16x8 pfa[ACH];
  float pfb[8];
  int am = tid / TPR, aks = (tid % TPR) * (ACH * 8);
  const __bf16* arow = A + (size_t)(m0 + am) * ldaK + aks;
  int bn = tid & 63, bks = (tid >> 6) * 8;
  int nk = (K + 63) >> 6;

#pragma unroll
  for (int c = 0; c < ACH; ++c) pfa[c] = *(const bf16x8*)(arow + c * 8);
#pragma unroll
  for (int i = 0; i < 8; ++i) { int k = bks + i; pfb[i] = (k < K) ? B[(size_t)k * N + n0 + bn] : 0.f; }
#pragma unroll
  for (int c = 0; c < ACH; ++c) *(bf16x8*)&As[0][swz(am, aks + c * 8)] = pfa[c];
  {
    __bf16 tb[8];
#pragma unroll
    for (int i = 0; i < 8; ++i) tb[i] = (__bf16)pfb[i];
    *(bf16x8*)&Bs[0][swz(bn, bks)] = *(bf16x8*)&tb[0];
  }
  __syncthreads();

  int cur = 0;
  for (int it = 0; it < nk; ++it) {
    bool more = (it + 1 < nk);
    if (more) {
      int k0 = (it + 1) * 64;
#pragma unroll
      for (int c = 0; c < ACH; ++c) pfa[c] = *(const bf16x8*)(arow + k0 + c * 8);
#pragma unroll
      for (int i = 0; i < 8; ++i) { int k = k0 + bks + i; pfb[i] = (k < K) ? B[(size_t)k * N + n0 + bn] : 0.f; }
    }
    const __bf16* Ac = As[cur];
    const __bf16* Bc = Bs[cur];
#pragma unroll
    for (int kk = 0; kk < 64; kk += 32) {
      bf16x8 av[MI], bv[NI];
#pragma unroll
      for (int mi = 0; mi < MI; ++mi) { int r = r0 + mi * 16 + lrow; av[mi] = *(const bf16x8*)&Ac[swz(r, kk + lk)]; }
#pragma unroll
      for (int ni = 0; ni < NI; ++ni) { int r = c0 + ni * 16 + lrow; bv[ni] = *(const bf16x8*)&Bc[swz(r, kk + lk)]; }
#pragma unroll
      for (int mi = 0; mi < MI; ++mi)
#pragma unroll
        for (int ni = 0; ni < NI; ++ni) acc[mi][ni] = MFMA16(av[mi], bv[ni], acc[mi][ni]);
    }
    if (more) {
#pragma unroll
      for (int c = 0; c < ACH; ++c) *(bf16x8*)&As[cur ^ 1][swz(am, aks + c * 8)] = pfa[c];
      __bf16 tb[8];
#pragma unroll
      for (int i = 0; i < 8; ++i) tb[i] = (__bf16)pfb[i];
      *(bf16x8*)&Bs[cur ^ 1][swz(bn, bks)] = *(bf16x8*)&tb[0];
      __syncthreads();
      cur ^= 1;
    }
  }
#pragma unroll
  for (int mi = 0; mi < MI; ++mi)
#pragma unroll
    for (int ni = 0; ni < NI; ++ni) {
      int colg = n0 + c0 + ni * 16 + lrow;
      float bvv = bias[colg];
#pragma unroll
      for (int reg = 0; reg < 4; ++reg) {
        int rowg = m0 + r0 + mi * 16 + (lane >> 4) * 4 + reg;
        C[(size_t)rowg * N + colg] = acc[mi][ni][reg] + bvv;
      }
    }
}

// ============ GEMM dual-output: same A, two B/bias/C sets (mh + q fused) ============
__global__ __launch_bounds__(512) void k_gemm2d(const __bf16* __restrict__ A, int ldaK,
                                                const float* __restrict__ B1,
                                                const float* __restrict__ bias1,
                                                float* __restrict__ C1, int N1,
                                                const float* __restrict__ B2,
                                                const float* __restrict__ bias2,
                                                float* __restrict__ C2, int N2,
                                                int K) {
  constexpr int BM = 64, MI = 2, NI = 1;
  __shared__ __align__(16) __bf16 As[2][BM * 64];
  __shared__ __align__(16) __bf16 Bs[2][64 * 64];
  int tid = threadIdx.x, lane = tid & 63, w = tid >> 6;
  int wr = w >> 2, wn = w & 3;
  int m0 = blockIdx.x * BM;
  int n0 = blockIdx.y * 64;
  const float* B; const float* bias; float* C; int N;
  if (n0 < N1) { B = B1; bias = bias1; C = C1; N = N1; }
  else         { B = B2; bias = bias2; C = C2; N = N2; n0 -= N1; }
  int lrow = lane & 15, lk = (lane >> 4) * 8;
  int r0 = wr * MI * 16, c0 = wn * NI * 16;
  f32x4 acc[MI][NI] = {};

  bf16x8 pfa;
  float pfb[8];
  int am = tid >> 3, aks = (tid & 7) * 8;
  const __bf16* arow = A + (size_t)(m0 + am) * ldaK + aks;
  int bn = tid & 63, bks = (tid >> 6) * 8;
  int nk = (K + 63) >> 6;

  pfa = *(const bf16x8*)(arow);
#pragma unroll
  for (int i = 0; i < 8; ++i) { int k = bks + i; pfb[i] = (k < K) ? B[(size_t)k * N + n0 + bn] : 0.f; }
  *(bf16x8*)&As[0][swz(am, aks)] = pfa;
  {
    __bf16 tb[8];
#pragma unroll
    for (int i = 0; i < 8; ++i) tb[i] = (__bf16)pfb[i];
    *(bf16x8*)&Bs[0][swz(bn, bks)] = *(bf16x8*)&tb[0];
  }
  __syncthreads();

  int cur = 0;
  for (int it = 0; it < nk; ++it) {
    bool more = (it + 1 < nk);
    if (more) {
      int k0 = (it + 1) * 64;
      pfa = *(const bf16x8*)(arow + k0);
#pragma unroll
      for (int i = 0; i < 8; ++i) { int k = k0 + bks + i; pfb[i] = (k < K) ? B[(size_t)k * N + n0 + bn] : 0.f; }
    }
    const __bf16* Ac = As[cur];
    const __bf16* Bc = Bs[cur];
#pragma unroll
    for (int kk = 0; kk < 64; kk += 32) {
      bf16x8 av[MI], bv[NI];
#pragma unroll
      for (int mi = 0; mi < MI; ++mi) { int r = r0 + mi * 16 + lrow; av[mi] = *(const bf16x8*)&Ac[swz(r, kk + lk)]; }
#pragma unroll
      for (int ni = 0; ni < NI; ++ni) { int r = c0 + ni * 16 + lrow; bv[ni] = *(const bf16x8*)&Bc[swz(r, kk + lk)]; }
#pragma unroll
      for (int mi = 0; mi < MI; ++mi)
#pragma unroll
        for (int ni = 0; ni < NI; ++ni) acc[mi][ni] = MFMA16(av[mi], bv[ni], acc[mi][ni]);
    }
    if (more) {
      *(bf16x8*)&As[cur ^ 1][swz(am, aks)] = pfa;
      __bf16 tb[8];
#pragma unroll
      for (int i = 0; i < 8; ++i) tb[i] = (__bf16)pfb[i];
      *(bf16x8*)&Bs[cur ^ 1][swz(bn, bks)] = *(bf16x8*)&tb[0];
      __syncthreads();
      cur ^= 1;
    }
  }
#pragma unroll
  for (int mi = 0; mi < MI; ++mi)
#pragma unroll
    for (int ni = 0; ni < NI; ++ni) {
      int colg = n0 + c0 + ni * 16 + lrow;
      float bvv = bias[colg];
#pragma unroll
      for (int reg = 0; reg < 4; ++reg) {
        int rowg = m0 + r0 + mi * 16 + (lane >> 4) * 4 + reg;
        C[(size_t)rowg * N + colg] = acc[mi][ni][reg] + bvv;
      }
    }
}

// ============ score v9: 256x256 tile, 8-wave quadrant-cooperative 4-phase rounds ============
// Per round (K-tile t, BK=64): 4 phases = C-quadrants (0,0),(1,0),(1,1),(0,1).
// All 8 waves cooperate on one 128x128 quadrant per phase (wave: 64x32 = 4x2 frags, 16 MFMA).
// Staging: one 16KB half-tile per phase into opposite dbuf (order A0,B0,A1,B1 of tile t+1).
// Waits: vmcnt(4) at phases 0/1/2 entry (2 half-tiles always in flight), barrier per phase.
// grid (128 m-tiles, 2 n-tiles). Output sc_part[row][2] (pre-softmax, V-contracted).
__global__ __launch_bounds__(512) void k_score9(const __bf16* __restrict__ enc_bf,
                                                const __bf16* __restrict__ W1t,
                                                const float* __restrict__ b1,
                                                const float* __restrict__ q,
                                                const float* __restrict__ V,
                                                float* __restrict__ sc_part) {
  __shared__ __align__(16) __bf16 Ah[2][2][8192];   // [dbuf][half][128*64]
  __shared__ __align__(16) __bf16 Bh[2][2][8192];
  __shared__ float red[4][256];
  int tid = threadIdx.x, lane = tid & 63, wv = tid >> 6;
  int wr = wv >> 2, wc = wv & 3;                    // wave pos within quadrant (2Mx4N)
  int lrow = lane & 15, lk = (lane >> 4) * 8;
  int m0 = blockIdx.x * 256, by = blockIdx.y, n0 = by * 256;

  f32x4 acc[4][4][2] = {};                          // [phase-quadrant][i][j]

  // ---- preload epilogue operands, then drain so in-loop vmcnt counts only gl_lds
  float Vv[2][2], B1v[2][2], Qv[2][2][2];
#pragma unroll
  for (int qc = 0; qc < 2; ++qc)
#pragma unroll
    for (int j = 0; j < 2; ++j) {
      int c = n0 + qc * 128 + wc * 32 + j * 16 + lrow;
      Vv[qc][j] = V[c];
      B1v[qc][j] = b1[c];
#pragma unroll
      for (int qr = 0; qr < 2; ++qr)
        Qv[qr][qc][j] = q[(size_t)(blockIdx.x * 2 + qr) * DECU + c];
    }
  asm volatile("s_waitcnt vmcnt(0)" ::: "memory");

  // ---- staging geometry: wave wv stages rows [wv*16, wv*16+16) of each 128-row half.
  // chunk (8 rows): lane l -> row +(l>>3), phys slot l&7; swizzled source slot (l&7)^((l>>3)&7).
  int srow = lane >> 3;
  int sslot = (lane & 7) ^ (srow & 7);
  const __bf16* aS = enc_bf + (size_t)(m0 + wv * 16 + srow) * 1024 + sslot * 8;
  const __bf16* bS = W1t + (size_t)(n0 + wv * 16 + srow) * 1024 + sslot * 8;

#define ST_A(HF, DB, KO) do { \
    gl_lds16(aS + (size_t)(HF) * 131072 + (KO), &Ah[DB][HF][wv * 1024]); \
    gl_lds16(aS + (size_t)(HF) * 131072 + 8192 + (KO), &Ah[DB][HF][wv * 1024 + 512]); } while (0)
#define ST_B(HF, DB, KO) do { \
    gl_lds16(bS + (size_t)(HF) * 131072 + (KO), &Bh[DB][HF][wv * 1024]); \
    gl_lds16(bS + (size_t)(HF) * 131072 + 8192 + (KO), &Bh[DB][HF][wv * 1024 + 512]); } while (0)

#define WORK(P, QR, QC) do { \
    const __bf16* Ab = &Ah[rd][QR][0]; \
    const __bf16* Bb = &Bh[rd][QC][0]; \
    __builtin_amdgcn_s_setprio(1); \
    _Pragma("unroll") \
    for (int kk = 0; kk < 64; kk += 32) { \
      bf16x8 av[4], bv[2]; \
      _Pragma("unroll") \
      for (int i = 0; i < 4; ++i) av[i] = *(const bf16x8*)&Ab[swz(wr * 64 + i * 16 + lrow, kk + lk)]; \
      _Pragma("unroll") \
      for (int j = 0; j < 2; ++j) bv[j] = *(const bf16x8*)&Bb[swz(wc * 32 + j * 16 + lrow, kk + lk)]; \
      _Pragma("unroll") \
      for (int i = 0; i < 4; ++i) \
        _Pragma("unroll") \
        for (int j = 0; j < 2; ++j) acc[P][i][j] = MFMA16(av[i], bv[j], acc[P][i][j]); \
    } \
    __builtin_amdgcn_s_setprio(0); } while (0)

  // ---- prologue: stage tile 0 into dbuf 0, issue order A0,B0,A1,B1
  ST_A(0, 0, 0);
  ST_B(0, 0, 0);
  ST_A(1, 0, 0);
  ST_B(1, 0, 0);

  for (int t = 0; t < 16; ++t) {
    int rd = t & 1, wd = rd ^ 1;
    size_t ko = (size_t)(t + 1) * 64;
    bool more = (t < 15);
    // ph0: Q(0,0) — needs A0(t),B0(t)
    asm volatile("s_waitcnt vmcnt(4)" ::: "memory");
    __builtin_amdgcn_s_barrier();
    if (more) ST_A(0, wd, ko);
    WORK(0, 0, 0);
    // ph1: Q(1,0) — needs A1(t)
    asm volatile("s_waitcnt vmcnt(4)" ::: "memory");
    __builtin_amdgcn_s_barrier();
    if (more) ST_B(0, wd, ko);
    WORK(1, 1, 0);
    // ph2: Q(1,1) — needs B1(t)
    asm volatile("s_waitcnt vmcnt(4)" ::: "memory");
    __builtin_amdgcn_s_barrier();
    if (more) ST_A(1, wd, ko);
    WORK(2, 1, 1);
    // ph3: Q(0,1) — operands already visible
    __builtin_amdgcn_s_barrier();
    if (more) ST_B(1, wd, ko);
    WORK(3, 0, 1);
  }
#undef ST_A
#undef ST_B
#undef WORK

  // ---- epilogue: tanh + V-dot; phase->quadrant map p:{(0,0),(1,0),(1,1),(0,1)}
  float psum[2][4][4] = {};
  {
    constexpr int QRv[4] = {0, 1, 1, 0};
    constexpr int QCv[4] = {0, 0, 1, 1};
#pragma unroll
    for (int p = 0; p < 4; ++p) {
      int qr = QRv[p], qc = QCv[p];
#pragma unroll
      for (int i = 0; i < 4; ++i)
#pragma unroll
        for (int j = 0; j < 2; ++j)
#pragma unroll
          for (int reg = 0; reg < 4; ++reg)
            psum[qr][i][reg] += Vv[qc][j] * fast_tanh(acc[p][i][j][reg] + B1v[qc][j] + Qv[qr][qc][j]);
    }
  }
#pragma unroll
  for (int off = 1; off < 16; off <<= 1)
#pragma unroll
    for (int qr = 0; qr < 2; ++qr)
#pragma unroll
      for (int i = 0; i < 4; ++i)
#pragma unroll
        for (int reg = 0; reg < 4; ++reg)
          psum[qr][i][reg] += __shfl_xor(psum[qr][i][reg], off);
  __syncthreads();
  if (lrow == 0) {
#pragma unroll
    for (int qr = 0; qr < 2; ++qr)
#pragma unroll
      for (int i = 0; i < 4; ++i)
#pragma unroll
        for (int reg = 0; reg < 4; ++reg)
          red[wc][qr * 128 + wr * 64 + i * 16 + (lane >> 4) * 4 + reg] = psum[qr][i][reg];
  }
  __syncthreads();
  if (tid < 256) {
    float s = red[0][tid] + red[1][tid] + red[2][tid] + red[3][tid];
    sc_part[(size_t)(m0 + tid) * 2 + by] = s;
  }
}

// ---------------- ctx v5: softmax + context (bf16 enc) + xi; grid (256 b, 8 col-chunks) ----------------
__global__ __launch_bounds__(256) void k_ctx5(const float* __restrict__ sc_part,
                                              const float* __restrict__ bV,
                                              const __bf16* __restrict__ enc_bf,
                                              const int* __restrict__ x,
                                              const float* __restrict__ emb,
                                              float* __restrict__ attn_out,
                                              __bf16* __restrict__ xi_bf) {
  int b = blockIdx.x, chunk = blockIdx.y, t = threadIdx.x;
  int lane = t & 63, w = t >> 6;
  __shared__ float a_s[S_];
  __shared__ float part[4][128];
  if (t < S_) {
    float2 p = *(const float2*)&sc_part[((size_t)b * 128 + t) * 2];
    a_s[t] = bV[0] + p.x + p.y;
  }
  __syncthreads();
  float mx = -INFINITY;
  for (int s = 0; s < S_; ++s) mx = fmaxf(mx, a_s[s]);
  float sum = 0.f;
  for (int s = 0; s < S_; ++s) sum += __expf(a_s[s] - mx);
  float inv = 1.f / sum;
  __syncthreads();
  if (t < S_) {
    float av = __expf(a_s[t] - mx) * inv;
    a_s[t] = av;
    if (chunk == 0) attn_out[(size_t)b * S_ + t] = av;
  }
  __syncthreads();
  int c0 = chunk * 128;
  float a0 = 0.f, a1 = 0.f;
  const __bf16* eb = enc_bf + ((size_t)b * S_ + w * 32) * ENCD + c0 + lane * 2;
#pragma unroll 8
  for (int s = 0; s < 32; ++s) {
    bf16x2 e = *(const bf16x2*)(eb + (size_t)s * ENCD);
    float av = a_s[w * 32 + s];
    a0 = fmaf(av, (float)e[0], a0);
    a1 = fmaf(av, (float)e[1], a1);
  }
  part[w][lane * 2 + 0] = a0;
  part[w][lane * 2 + 1] = a1;
  __syncthreads();
  if (t < 128) {
    float v = part[0][t] + part[1][t] + part[2][t] + part[3][t];
    xi_bf[(size_t)b * KPADX + c0 + t] = (__bf16)v;
  }
  if (chunk == 0) {
    int xb = x[b];
    if (t < 75) {
      float4 f = *(const float4*)&emb[(size_t)xb * EMB_ + t * 4];
      bf16x4 o4 = {(__bf16)f.x, (__bf16)f.y, (__bf16)f.z, (__bf16)f.w};
      *(bf16x4*)&xi_bf[(size_t)b * KPADX + ENCD + t * 4] = o4;
    } else if (t < 80) {
      bf16x4 z = {(__bf16)0.f, (__bf16)0.f, (__bf16)0.f, (__bf16)0.f};
      *(bf16x4*)&xi_bf[(size_t)b * KPADX + INDIM + (t - 75) * 4] = z;
    }
  }
}

// ---------------- GRU gates (+ h in bf16) ----------------
__global__ __launch_bounds__(256) void k_gates(const float* __restrict__ mx,
                                               const float* __restrict__ mh,
                                               const float* __restrict__ state,
                                               float* __restrict__ h_out,
                                               __bf16* __restrict__ h_bf) {
  int idx = blockIdx.x * 256 + threadIdx.x;
  int b = idx >> 10, j = idx & 1023;
  const float* mxr = mx + (size_t)b * G3;
  const float* mhr = mh + (size_t)b * G3;
  float z = 1.f / (1.f + __expf(-(mxr[j] + mhr[j])));
  float r = 1.f / (1.f + __expf(-(mxr[UNITS + j] + mhr[UNITS + j])));
  float hh = tanhf(mxr[2 * UNITS + j] + r * mhr[2 * UNITS + j]);
  float st = state[idx];
  float h = z * st + (1.f - z) * hh;
  h_out[idx] = h;
  h_bf[idx] = (__bf16)h;
}

// ---------------- register-resident vocab softmax ----------------
__global__ __launch_bounds__(1024) void k_softmax(float* __restrict__ logits) {
  int b = blockIdx.x, t = threadIdx.x;
  int lane = t & 63, w = t >> 6;
  float4* row4 = (float4*)(logits + (size_t)b * VOCAB);  // 8000 float4
  __shared__ float redm[16];
  __shared__ float reds[16];
  float4 v[8];
  float m = -INFINITY;
#pragma unroll
  for (int i = 0; i < 8; ++i) {
    int i4 = i * 1024 + t;
    if (i4 < 8000) {
      v[i] = row4[i4];
      m = fmaxf(m, fmaxf(fmaxf(v[i].x, v[i].y), fmaxf(v[i].z, v[i].w)));
    } else {
      v[i] = make_float4(-INFINITY, -INFINITY, -INFINITY, -INFINITY);
    }
  }
#pragma unroll
  for (int o = 32; o >= 1; o >>= 1) m = fmaxf(m, __shfl_xor(m, o));
  if (lane == 0) redm[w] = m;
  __syncthreads();
  float m2 = -INFINITY;
#pragma unroll
  for (int i = 0; i < 16; ++i) m2 = fmaxf(m2, redm[i]);
  float s = 0.f;
#pragma unroll
  for (int i = 0; i < 8; ++i) {
    v[i].x = __expf(v[i].x - m2);
    v[i].y = __expf(v[i].y - m2);
    v[i].z = __expf(v[i].z - m2);
    v[i].w = __expf(v[i].w - m2);
    s += v[i].x + v[i].y + v[i].z + v[i].w;
  }
#pragma unroll
  for (int o = 32; o >= 1; o >>= 1) s += __shfl_xor(s, o);
  if (lane == 0) reds[w] = s;
  __syncthreads();
  float s2 = 0.f;
#pragma unroll
  for (int i = 0; i < 16; ++i) s2 += reds[i];
  float inv = 1.f / s2;
#pragma unroll
  for (int i = 0; i < 8; ++i) {
    int i4 = i * 1024 + t;
    if (i4 < 8000)
      row4[i4] = make_float4(v[i].x * inv, v[i].y * inv, v[i].z * inv, v[i].w * inv);
  }
}

extern "C" void kernel_launch(void* const* d_in, const int* in_sizes, int n_in,
                              void* d_out, int out_size, void* d_ws, size_t ws_size,
                              hipStream_t stream) {
  const int*   x     = (const int*)d_in[0];
  const float* state = (const float*)d_in[1];
  const float* enc   = (const float*)d_in[2];
  const float* emb   = (const float*)d_in[3];
  const float* W1    = (const float*)d_in[4];
  const float* b1    = (const float*)d_in[5];
  const float* W2    = (const float*)d_in[6];
  const float* b2    = (const float*)d_in[7];
  const float* V     = (const float*)d_in[8];
  const float* bV    = (const float*)d_in[9];
  const float* gru_k = (const float*)d_in[10];
  const float* gru_rk= (const float*)d_in[11];
  const float* gru_b = (const float*)d_in[12];
  const float* fc_W  = (const float*)d_in[13];
  const float* fc_b  = (const float*)d_in[14];

  float* out   = (float*)d_out;
  float* probs = out;                               // 256*32000
  float* h_out = out + (size_t)B_ * VOCAB;          // 256*1024
  float* attn  = h_out + (size_t)B_ * UNITS;        // 256*128

  // ws layout (bytes), 16B-aligned offsets:
  char* wsb = (char*)d_ws;
  const size_t ENC_BF_BYTES = (size_t)B_ * S_ * ENCD * 2;        // 67,108,864
  __bf16* enc_bf  = (__bf16*)wsb;
  __bf16* W1t     = (__bf16*)(wsb + ENC_BF_BYTES);                // 1MB
  __bf16* state_bf= (__bf16*)(wsb + ENC_BF_BYTES + 1048576);      // 0.5MB
  __bf16* xi_bf   = (__bf16*)(wsb + ENC_BF_BYTES + 1572864);      // 688128
  __bf16* h_bf    = (__bf16*)(wsb + ENC_BF_BYTES + 2260992);      // 0.5MB
  float*  q       = (float*)(wsb + ENC_BF_BYTES + 2785280);       // 0.5MB
  float*  sc_part = (float*)(wsb + ENC_BF_BYTES + 3309568);       // 0.5MB
  float*  mx      = (float*)(wsb + ENC_BF_BYTES + 3833856);       // 3MB
  float*  mh      = (float*)(wsb + ENC_BF_BYTES + 6979584);       // 3MB

  k_prep<<<4352, 256, 0, stream>>>(enc, enc_bf, state, state_bf);
  k_w1t<<<512, 1024, 0, stream>>>(W1, W1t);
  // mh = state @ gru_rk + gru_b[1]  AND  q = state @ W2 + b2 (fused dual GEMM)
  k_gemm2d<<<dim3(4, 56), 512, 0, stream>>>(state_bf, UNITS,
                                            gru_rk, gru_b + G3, mh, G3,
                                            W2, b2, q, DECU, UNITS);
  // score partials: 256^2-tile 8-wave quadrant-cooperative counted-vmcnt pipeline
  k_score9<<<dim3(128, 2), 512, 0, stream>>>(enc_bf, W1t, b1, q, V, sc_part);
  // softmax + context + xi
  k_ctx5<<<dim3(B_, 8), 256, 0, stream>>>(sc_part, bV, enc_bf, x, emb, attn, xi_bf);
  // GRU input GEMM
  k_gemm2<64><<<dim3(4, 48), 512, 0, stream>>>(xi_bf, KPADX, gru_k, gru_b, mx, INDIM, G3);
  // gates -> h
  k_gates<<<(B_ * UNITS) / 256, 256, 0, stream>>>(mx, mh, state, h_out, h_bf);
  // FC logits
  k_gemm2<256><<<dim3(1, VOCAB / 64), 512, 0, stream>>>(h_bf, UNITS, fc_W, fc_b, probs, UNITS, VOCAB);
  // vocab softmax
  k_softmax<<<B_, 1024, 0, stream>>>(probs);
}